// Round 1
// baseline (10367.146 us; speedup 1.0000x reference)
//
#include <hip/hip_runtime.h>
#include <cmath>

namespace {

constexpr int kB = 8, kN = 515, kD = 1024, kH = 8, kDH = 64, kL = 4;
constexpr int kFF = 4096, kROT = 32;
constexpr int kNK = kN + 1;        // 516 keys (null + N)
constexpr int kM = kB * kN;        // 4120 token rows
constexpr float kEPS = 1e-5f;

__device__ __forceinline__ float wave_sum(float v) {
#pragma unroll
    for (int o = 32; o > 0; o >>= 1) v += __shfl_xor(v, o);
    return v;
}
__device__ __forceinline__ float wave_max(float v) {
#pragma unroll
    for (int o = 32; o > 0; o >>= 1) v = fmaxf(v, __shfl_xor(v, o));
    return v;
}

// ---------------- LayerNorm family ----------------
// 256 threads, one row of kD=1024 per block (float4 per thread).
// MODE 0: out = LN(in)*g
// MODE 1: out += LN(in)*g        (residual add into out)
// MODE 2: out = LN(in/max(in))*g (stable LN)
template<int MODE>
__global__ void ln_kernel(const float* __restrict__ in, const float* __restrict__ g,
                          float* __restrict__ out) {
    int row = blockIdx.x;
    const float4* inr = (const float4*)(in + (size_t)row * kD);
    float4 v = inr[threadIdx.x];
    __shared__ float red[4];
    int lane = threadIdx.x & 63, wid = threadIdx.x >> 6;

    if (MODE == 2) {
        float mx = fmaxf(fmaxf(v.x, v.y), fmaxf(v.z, v.w));
        mx = wave_max(mx);
        if (lane == 0) red[wid] = mx;
        __syncthreads();
        mx = fmaxf(fmaxf(red[0], red[1]), fmaxf(red[2], red[3]));
        __syncthreads();
        float inv = 1.0f / mx;
        v.x *= inv; v.y *= inv; v.z *= inv; v.w *= inv;
    }

    float s = v.x + v.y + v.z + v.w;
    s = wave_sum(s);
    if (lane == 0) red[wid] = s;
    __syncthreads();
    float mean = (red[0] + red[1] + red[2] + red[3]) * (1.0f / kD);
    __syncthreads();

    float dx = v.x - mean, dy = v.y - mean, dz = v.z - mean, dw = v.w - mean;
    float ss = dx * dx + dy * dy + dz * dz + dw * dw;
    ss = wave_sum(ss);
    if (lane == 0) red[wid] = ss;
    __syncthreads();
    float var = (red[0] + red[1] + red[2] + red[3]) * (1.0f / kD);
    float r = 1.0f / sqrtf(var + kEPS);

    float4 g4 = ((const float4*)g)[threadIdx.x];
    float4 o4 = make_float4(dx * r * g4.x, dy * r * g4.y, dz * r * g4.z, dw * r * g4.w);
    float4* op = (float4*)(out + (size_t)row * kD);
    if (MODE == 1) {
        float4 c = op[threadIdx.x];
        o4.x += c.x; o4.y += c.y; o4.z += c.z; o4.w += c.w;
    }
    op[threadIdx.x] = o4;
}

// ---------------- fp32 tiled GEMM ----------------
// C[M,N] = A[M,K] @ B[K,N]  (+bias / +=C per EPI)
// Tile: BM=64*GM, BN=64*GN, BK=16; 256 threads; per-thread micro-tile 4*GM x 4*GN
// arranged as GM/GN groups of 64 so LDS float4 reads are stride-16B (2-way, free).
template<int GM, int GN, int EPI>  // EPI: 0 store, 1 store+bias[col], 2 C += acc
__global__ void gemm_kernel(const float* __restrict__ A, const float* __restrict__ Bm,
                            float* __restrict__ C, const float* __restrict__ bias,
                            int Mm, int Nn, int Kk) {
    constexpr int BM = 64 * GM, BN = 64 * GN, BK = 16;
    __shared__ __align__(16) float As[BK][BM + 4];
    __shared__ __align__(16) float Bs[BK][BN + 4];
    const int m0 = blockIdx.y * BM, n0 = blockIdx.x * BN;
    const int t = threadIdx.x;
    const int tx = t & 15, ty = (t >> 4) & 15;
    const int kA = t & 15, rA = t >> 4;
    const int jBc = t & 63, kB0 = t >> 6;

    float acc[GM * 4][GN * 4];
#pragma unroll
    for (int i = 0; i < GM * 4; ++i)
#pragma unroll
        for (int j = 0; j < GN * 4; ++j) acc[i][j] = 0.f;

    for (int k0 = 0; k0 < Kk; k0 += BK) {
#pragma unroll
        for (int j = 0; j < 4 * GM; ++j) {
            int r = m0 + rA + 16 * j;
            As[kA][rA + 16 * j] = (r < Mm) ? A[(size_t)r * Kk + k0 + kA] : 0.f;
        }
#pragma unroll
        for (int s = 0; s < 4; ++s)
#pragma unroll
            for (int gq = 0; gq < GN; ++gq) {
                int kk = kB0 + 4 * s;
                Bs[kk][jBc + 64 * gq] = Bm[(size_t)(k0 + kk) * Nn + n0 + jBc + 64 * gq];
            }
        __syncthreads();
#pragma unroll
        for (int kk = 0; kk < BK; ++kk) {
            float4 af[GM], bf[GN];
#pragma unroll
            for (int gm = 0; gm < GM; ++gm) af[gm] = *(const float4*)&As[kk][64 * gm + ty * 4];
#pragma unroll
            for (int gn = 0; gn < GN; ++gn) bf[gn] = *(const float4*)&Bs[kk][64 * gn + tx * 4];
#pragma unroll
            for (int gm = 0; gm < GM; ++gm) {
                const float av[4] = {af[gm].x, af[gm].y, af[gm].z, af[gm].w};
#pragma unroll
                for (int gn = 0; gn < GN; ++gn) {
                    const float bv[4] = {bf[gn].x, bf[gn].y, bf[gn].z, bf[gn].w};
#pragma unroll
                    for (int a = 0; a < 4; ++a)
#pragma unroll
                        for (int bb = 0; bb < 4; ++bb)
                            acc[gm * 4 + a][gn * 4 + bb] =
                                fmaf(av[a], bv[bb], acc[gm * 4 + a][gn * 4 + bb]);
                }
            }
        }
        __syncthreads();
    }

#pragma unroll
    for (int gm = 0; gm < GM; ++gm)
#pragma unroll
        for (int a = 0; a < 4; ++a) {
            int r = m0 + 64 * gm + ty * 4 + a;
            if (r >= Mm) continue;
#pragma unroll
            for (int gn = 0; gn < GN; ++gn) {
                int c = n0 + 64 * gn + tx * 4;
                float4 o = make_float4(acc[gm * 4 + a][gn * 4 + 0], acc[gm * 4 + a][gn * 4 + 1],
                                       acc[gm * 4 + a][gn * 4 + 2], acc[gm * 4 + a][gn * 4 + 3]);
                float4* cp = (float4*)(C + (size_t)r * Nn + c);
                if (EPI == 1) {
                    const float4 b4 = *(const float4*)(bias + c);
                    o.x += b4.x; o.y += b4.y; o.z += b4.z; o.w += b4.w;
                }
                if (EPI == 2) {
                    float4 c4 = *cp;
                    o.x += c4.x; o.y += c4.y; o.z += c4.z; o.w += c4.w;
                }
                *cp = o;
            }
        }
}

// ---------------- fused FF1 + SwiGLU ----------------
// out[M, FF] = (A @ W[:, :FF]) * silu(A @ W[:, FF:])   with W = Wff1[l] (K=1024, 2*FF wide)
__global__ void gemm_glu_kernel(const float* __restrict__ A, const float* __restrict__ W,
                                float* __restrict__ C, int Mm) {
    constexpr int BM = 128, BN = 64, BK = 16, Kk = kD, Nw = 2 * kFF;
    __shared__ __align__(16) float As[BK][BM + 4];
    __shared__ __align__(16) float Ba[BK][BN + 4];
    __shared__ __align__(16) float Bg[BK][BN + 4];
    const int m0 = blockIdx.y * BM, n0 = blockIdx.x * BN;
    const int t = threadIdx.x;
    const int tx = t & 15, ty = (t >> 4) & 15;
    const int kA = t & 15, rA = t >> 4;
    const int jBc = t & 63, kB0 = t >> 6;

    float acca[8][4] = {}, accg[8][4] = {};
    for (int k0 = 0; k0 < Kk; k0 += BK) {
#pragma unroll
        for (int j = 0; j < 8; ++j) {
            int r = m0 + rA + 16 * j;
            As[kA][rA + 16 * j] = (r < Mm) ? A[(size_t)r * Kk + k0 + kA] : 0.f;
        }
#pragma unroll
        for (int s = 0; s < 4; ++s) {
            int kk = kB0 + 4 * s;
            Ba[kk][jBc] = W[(size_t)(k0 + kk) * Nw + n0 + jBc];
            Bg[kk][jBc] = W[(size_t)(k0 + kk) * Nw + kFF + n0 + jBc];
        }
        __syncthreads();
#pragma unroll
        for (int kk = 0; kk < BK; ++kk) {
            float4 a0 = *(const float4*)&As[kk][ty * 4];
            float4 a1 = *(const float4*)&As[kk][64 + ty * 4];
            float4 ba = *(const float4*)&Ba[kk][tx * 4];
            float4 bg = *(const float4*)&Bg[kk][tx * 4];
            const float av[8] = {a0.x, a0.y, a0.z, a0.w, a1.x, a1.y, a1.z, a1.w};
            const float bav[4] = {ba.x, ba.y, ba.z, ba.w};
            const float bgv[4] = {bg.x, bg.y, bg.z, bg.w};
#pragma unroll
            for (int a = 0; a < 8; ++a)
#pragma unroll
                for (int b2 = 0; b2 < 4; ++b2) {
                    acca[a][b2] = fmaf(av[a], bav[b2], acca[a][b2]);
                    accg[a][b2] = fmaf(av[a], bgv[b2], accg[a][b2]);
                }
        }
        __syncthreads();
    }
#pragma unroll
    for (int a = 0; a < 8; ++a) {
        int r = m0 + (a < 4 ? ty * 4 + a : 64 + ty * 4 + (a - 4));
        if (r >= Mm) continue;
        float vv[4];
#pragma unroll
        for (int b2 = 0; b2 < 4; ++b2) {
            float gv = accg[a][b2];
            float sg = gv / (1.0f + expf(-gv));
            vv[b2] = acca[a][b2] * sg;
        }
        *(float4*)(C + (size_t)r * kFF + n0 + tx * 4) = make_float4(vv[0], vv[1], vv[2], vv[3]);
    }
}

// ---------------- rotary + l2norm ----------------
// q layout: (b, n, h, d) rows of 64. In-place rotary on d<32 then l2-normalize row.
__global__ void qrot_kernel(float* __restrict__ q) {
    int row = blockIdx.x * 4 + (threadIdx.x >> 6);
    int lane = threadIdx.x & 63;
    int pos = (row / kH) % kN;
    float t = q[(size_t)row * kDH + lane];
    float partner = __shfl_xor(t, 1);
    if (lane < kROT) {
        float e = (float)(lane & ~1) / (float)kROT;
        float inv = powf(10000.0f, -e);
        float ang = (float)pos * inv;
        float c = cosf(ang), s = sinf(ang);
        t = (lane & 1) ? fmaf(t, c, partner * s) : fmaf(t, c, -partner * s);
    }
    float ss = wave_sum(t * t);
    q[(size_t)row * kDH + lane] = t * (1.0f / sqrtf(ss));
}

// kv: (b*n, 128) -> k,v: (b, 516, 64); row 0 of each b is the (un-rotated) null kv.
__global__ void krot_kernel(const float* __restrict__ kv, const float* __restrict__ nullkv,
                            float* __restrict__ kk, float* __restrict__ vv) {
    int row = blockIdx.x * 4 + (threadIdx.x >> 6);
    int lane = threadIdx.x & 63;
    int b = row / kNK, jj = row % kNK;
    float tk, tv;
    if (jj == 0) {
        tk = nullkv[lane];
        tv = nullkv[64 + lane];
    } else {
        size_t base = ((size_t)(b * kN + jj - 1)) * 128;
        tk = kv[base + lane];
        tv = kv[base + 64 + lane];
    }
    float partner = __shfl_xor(tk, 1);
    if (jj != 0 && lane < kROT) {
        float e = (float)(lane & ~1) / (float)kROT;
        float inv = powf(10000.0f, -e);
        float ang = (float)(jj - 1) * inv;
        float c = cosf(ang), s = sinf(ang);
        tk = (lane & 1) ? fmaf(tk, c, partner * s) : fmaf(tk, c, -partner * s);
    }
    float ss = wave_sum(tk * tk);
    kk[(size_t)row * kDH + lane] = tk * (1.0f / sqrtf(ss));
    vv[(size_t)row * kDH + lane] = tv;
}

// ---------------- relpos bias table (layer-independent) ----------------
// bias[h][i][j] = emb[bucket(i,j)][h], i in [0,N), j in [0,NK)
__global__ void bias_kernel(const float* __restrict__ emb, float* __restrict__ bias) {
    int idx = blockIdx.x * 256 + threadIdx.x;
    if (idx >= kN * kNK) return;
    int i = idx / kNK, jj = idx % kNK;
    int nn = i - jj; if (nn < 0) nn = 0;
    int bucket;
    if (nn < 16) bucket = nn;
    else {
        float lf = logf((float)nn * (1.0f / 16.0f));
        int vl = 16 + (int)(lf / logf(8.0f) * 16.0f);
        bucket = vl < 31 ? vl : 31;
    }
#pragma unroll
    for (int h = 0; h < kH; ++h)
        bias[((size_t)h * kN + i) * kNK + jj] = emb[bucket * kH + h];
}

// ---------------- attention ----------------
// 1 wave per (b,h,i). scores s_j = 16*dot(q^,k^_j) + bias[h,i,j], j in [0, i+1].
__global__ void attn_kernel(const float* __restrict__ q, const float* __restrict__ k,
                            const float* __restrict__ v, const float* __restrict__ bias,
                            float* __restrict__ o) {
    int idx = blockIdx.x;
    int i = idx % kN;
    int bh = idx / kN;
    int h = bh % kH, b = bh / kH;
    int lane = threadIdx.x;
    __shared__ __align__(16) float qs[kDH];
    __shared__ float sc[kNK];

    qs[lane] = q[((size_t)(b * kN + i) * kH + h) * kDH + lane];
    __syncthreads();

    const int jmax = i + 2;  // allowed keys: j <= i+1
    const float* kb = k + (size_t)b * kNK * kDH;
    const float* bp = bias + ((size_t)h * kN + i) * kNK;

    float mloc = -1e30f;
    for (int j = lane; j < jmax; j += 64) {
        const float4* kr = (const float4*)(kb + (size_t)j * kDH);
        float s = 0.f;
#pragma unroll
        for (int d4 = 0; d4 < 16; ++d4) {
            float4 k4 = kr[d4];
            float4 q4 = *(const float4*)&qs[d4 * 4];
            s += q4.x * k4.x + q4.y * k4.y + q4.z * k4.z + q4.w * k4.w;
        }
        s = 16.0f * s + bp[j];
        sc[j] = s;
        mloc = fmaxf(mloc, s);
    }
    mloc = wave_max(mloc);
    float ssum = 0.f;
    for (int j = lane; j < jmax; j += 64) {
        float p = expf(sc[j] - mloc);
        sc[j] = p;
        ssum += p;
    }
    ssum = wave_sum(ssum);
    __syncthreads();

    float inv = 1.0f / ssum;
    const float* vb = v + (size_t)b * kNK * kDH;
    float acc = 0.f;
#pragma unroll 4
    for (int j = 0; j < jmax; ++j) acc = fmaf(sc[j], vb[(size_t)j * kDH + lane], acc);
    o[((size_t)(b * kN + i) * kH + h) * kDH + lane] = acc * inv;
}

}  // namespace

extern "C" void kernel_launch(void* const* d_in, const int* in_sizes, int n_in,
                              void* d_out, int out_size, void* d_ws, size_t ws_size,
                              hipStream_t stream) {
    const float* x_in   = (const float*)d_in[0];
    const float* attn_g = (const float*)d_in[1];
    const float* Wq     = (const float*)d_in[2];
    const float* Wkv    = (const float*)d_in[3];
    const float* bkv    = (const float*)d_in[4];
    const float* nullkv = (const float*)d_in[5];
    const float* Wo     = (const float*)d_in[6];
    const float* out_g  = (const float*)d_in[7];
    const float* ff_g   = (const float*)d_in[8];
    const float* Wff1   = (const float*)d_in[9];
    const float* Wff2   = (const float*)d_in[10];
    const float* emb    = (const float*)d_in[11];
    const float* fin_g  = (const float*)d_in[12];
    const float* Wproj  = (const float*)d_in[13];
    float* out = (float*)d_out;

    float* ws = (float*)d_ws;
    size_t off = 0;
    float* bx   = ws + off; off += (size_t)kM * kD;          // residual stream
    float* bxn  = ws + off; off += (size_t)kM * kD;          // LN output
    float* bt   = ws + off; off += (size_t)kM * kD;          // GEMM temp
    float* bq   = ws + off; off += (size_t)kM * kH * kDH;    // q
    float* bo   = ws + off; off += (size_t)kM * kH * kDH;    // attn out
    float* bkvb = ws + off; off += (size_t)kM * 2 * kDH;     // kv
    float* bk   = ws + off; off += (size_t)kB * kNK * kDH;   // keys (with null)
    float* bv   = ws + off; off += (size_t)kB * kNK * kDH;   // values (with null)
    float* bff  = ws + off; off += (size_t)kM * kFF;         // a*silu(g)
    float* bbias= ws + off; off += (size_t)kH * kN * kNK;    // relpos bias

    hipMemcpyAsync(bx, x_in, (size_t)kM * kD * sizeof(float), hipMemcpyDeviceToDevice, stream);
    bias_kernel<<<(kN * kNK + 255) / 256, 256, 0, stream>>>(emb, bbias);

    for (int l = 0; l < kL; ++l) {
        ln_kernel<0><<<kM, 256, 0, stream>>>(bx, attn_g + (size_t)l * kD, bxn);
        gemm_kernel<1, 1, 0><<<dim3(8, 65), 256, 0, stream>>>(
            bxn, Wq + (size_t)l * kD * 512, bq, nullptr, kM, 512, kD);
        gemm_kernel<1, 1, 1><<<dim3(2, 65), 256, 0, stream>>>(
            bxn, Wkv + (size_t)l * kD * 128, bkvb, bkv + (size_t)l * 128, kM, 128, kD);
        qrot_kernel<<<kM * kH / 4, 256, 0, stream>>>(bq);
        krot_kernel<<<kB * kNK / 4, 256, 0, stream>>>(bkvb, nullkv + (size_t)l * 128, bk, bv);
        attn_kernel<<<kB * kH * kN, 64, 0, stream>>>(bq, bk, bv, bbias, bo);
        gemm_kernel<2, 1, 0><<<dim3(16, 33), 256, 0, stream>>>(
            bo, Wo + (size_t)l * 512 * kD, bt, nullptr, kM, kD, 512);
        ln_kernel<1><<<kM, 256, 0, stream>>>(bt, out_g + (size_t)l * kD, bx);
        ln_kernel<0><<<kM, 256, 0, stream>>>(bx, ff_g + (size_t)l * kD, bxn);
        gemm_glu_kernel<<<dim3(64, 33), 256, 0, stream>>>(
            bxn, Wff1 + (size_t)l * kD * 2 * kFF, bff, kM);
        gemm_kernel<2, 1, 2><<<dim3(16, 33), 256, 0, stream>>>(
            bff, Wff2 + (size_t)l * kFF * kD, bx, nullptr, kM, kD, kFF);
    }

    ln_kernel<2><<<kM, 256, 0, stream>>>(bx, fin_g, bxn);
    gemm_kernel<2, 1, 0><<<dim3(16, 33), 256, 0, stream>>>(
        bxn, Wproj, out, nullptr, kM, kD, kD);
}

// Round 4
// 3283.988 us; speedup vs baseline: 3.1569x; 3.1569x over previous
//
#include <hip/hip_runtime.h>
#include <cmath>

namespace {

constexpr int kB = 8, kN = 515, kD = 1024, kH = 8, kDH = 64, kL = 4;
constexpr int kFF = 4096, kROT = 32;
constexpr int kNK = kN + 1;        // 516 keys (null + N)
constexpr int kM = kB * kN;        // 4120 token rows
constexpr float kEPS = 1e-5f;

typedef _Float16 half_t;
typedef _Float16 half8 __attribute__((ext_vector_type(8)));
typedef float f32x4 __attribute__((ext_vector_type(4)));

__device__ __forceinline__ float wave_sum(float v) {
#pragma unroll
    for (int o = 32; o > 0; o >>= 1) v += __shfl_xor(v, o);
    return v;
}
__device__ __forceinline__ float wave_max(float v) {
#pragma unroll
    for (int o = 32; o > 0; o >>= 1) v = fmaxf(v, __shfl_xor(v, o));
    return v;
}

// ---------------- LayerNorm family ----------------
template<int MODE>  // 0: out=LN(in)*g   1: out+=LN(in)*g   2: out=LN(in/max)*g
__global__ void ln_kernel(const float* __restrict__ in, const float* __restrict__ g,
                          float* __restrict__ out) {
    int row = blockIdx.x;
    const float4* inr = (const float4*)(in + (size_t)row * kD);
    float4 v = inr[threadIdx.x];
    __shared__ float red[4];
    int lane = threadIdx.x & 63, wid = threadIdx.x >> 6;

    if (MODE == 2) {
        float mx = fmaxf(fmaxf(v.x, v.y), fmaxf(v.z, v.w));
        mx = wave_max(mx);
        if (lane == 0) red[wid] = mx;
        __syncthreads();
        mx = fmaxf(fmaxf(red[0], red[1]), fmaxf(red[2], red[3]));
        __syncthreads();
        float inv = 1.0f / mx;
        v.x *= inv; v.y *= inv; v.z *= inv; v.w *= inv;
    }

    float s = v.x + v.y + v.z + v.w;
    s = wave_sum(s);
    if (lane == 0) red[wid] = s;
    __syncthreads();
    float mean = (red[0] + red[1] + red[2] + red[3]) * (1.0f / kD);
    __syncthreads();

    float dx = v.x - mean, dy = v.y - mean, dz = v.z - mean, dw = v.w - mean;
    float ss = dx * dx + dy * dy + dz * dz + dw * dw;
    ss = wave_sum(ss);
    if (lane == 0) red[wid] = ss;
    __syncthreads();
    float var = (red[0] + red[1] + red[2] + red[3]) * (1.0f / kD);
    float r = 1.0f / sqrtf(var + kEPS);

    float4 g4 = ((const float4*)g)[threadIdx.x];
    float4 o4 = make_float4(dx * r * g4.x, dy * r * g4.y, dz * r * g4.z, dw * r * g4.w);
    float4* op = (float4*)(out + (size_t)row * kD);
    if (MODE == 1) {
        float4 c = op[threadIdx.x];
        o4.x += c.x; o4.y += c.y; o4.z += c.z; o4.w += c.w;
    }
    op[threadIdx.x] = o4;
}

// ------- weight transpose+convert: W[k][n] f32 -> Wt[row'(n)][k] f16 -------
// ILV=0: row' = rowOff + n.
// ILV=1 (Wff1 a/g interleave): n<FF: row' = (n>>4)*32 + (n&15);
//                              n>=FF: c=n-FF, row' = (c>>4)*32 + 16 + (c&15).
template<int ILV>
__global__ void tcvt_kernel(const float* __restrict__ src, half_t* __restrict__ dst,
                            int K, int N, int pitch, int rowOff) {
    __shared__ float tile[32][33];
    int tx = threadIdx.x & 31, ty = threadIdx.x >> 5;  // 256 thr: ty 0..7
    int n0 = blockIdx.x * 32, k0 = blockIdx.y * 32;
#pragma unroll
    for (int j = 0; j < 4; ++j)
        tile[ty + 8 * j][tx] = src[(size_t)(k0 + ty + 8 * j) * N + n0 + tx];
    __syncthreads();
#pragma unroll
    for (int j = 0; j < 4; ++j) {
        int n = n0 + ty + 8 * j;
        int rowp;
        if (ILV == 0) {
            rowp = rowOff + n;
        } else {
            if (n < kFF) rowp = ((n >> 4) << 5) + (n & 15);
            else { int c = n - kFF; rowp = ((c >> 4) << 5) + 16 + (c & 15); }
        }
        dst[(size_t)rowp * pitch + k0 + tx] = (half_t)tile[tx][ty + 8 * j];
    }
}

// ---------------- fp16 MFMA GEMM ----------------
// C[M,N] = A[M,K] @ Bt[N,K]^T.  128x128 tile, BK=32, 4 waves (2x2), wave=64x64 (4x4 frags).
// EPI: 0 f32 store, 1 qkv split (+bias on kv), 2 f32 +=, 3 f16 store,
//      4 glu: interleaved a/g cols -> Ch[row][c] = a*silu(g), Ch pitch Nn/2
template<int AF16, int EPI>
__global__ __launch_bounds__(256)
void mm_kernel(const float* __restrict__ Af, const half_t* __restrict__ Ah,
               const half_t* __restrict__ Bt,
               float* __restrict__ Cf, half_t* __restrict__ Ch,
               float* __restrict__ C2, const float* __restrict__ bias,
               int Mm, int Nn, int Kk) {
    constexpr int PADK = 40;  // 32 f16 + 8 pad -> 80B row stride
    __shared__ half_t As[128 * PADK];
    __shared__ half_t Bs[128 * PADK];
    const int m0 = blockIdx.y * 128, n0 = blockIdx.x * 128;
    const int t = threadIdx.x, lane = t & 63, wid = t >> 6;
    const int wr = wid >> 1, wc = wid & 1;
    const int srow = t >> 1, skh = (t & 1) * 16;

    f32x4 acc[4][4] = {};

    const int arow = m0 + srow;
    const bool aval = arow < Mm;
    const float*  aptr  = Af + (size_t)arow * Kk + skh;
    const half_t* ahptr = Ah + (size_t)arow * Kk + skh;
    const half_t* bptr  = Bt + (size_t)(n0 + srow) * Kk + skh;
    half_t* asl = &As[srow * PADK + skh];
    half_t* bsl = &Bs[srow * PADK + skh];

    const int kg = (lane >> 4) * 8;   // k-offset of this lane's fragment
    const int rl = lane & 15;

    for (int k0 = 0; k0 < Kk; k0 += 32) {
        half8 h0 = {0, 0, 0, 0, 0, 0, 0, 0}, h1 = {0, 0, 0, 0, 0, 0, 0, 0};
        if (AF16) {
            if (aval) { h0 = *(const half8*)ahptr; h1 = *(const half8*)(ahptr + 8); }
            ahptr += 32;
        } else {
            if (aval) {
                const float4* a4 = (const float4*)aptr;
                float4 f0 = a4[0], f1 = a4[1], f2 = a4[2], f3 = a4[3];
                h0 = half8{(half_t)f0.x, (half_t)f0.y, (half_t)f0.z, (half_t)f0.w,
                           (half_t)f1.x, (half_t)f1.y, (half_t)f1.z, (half_t)f1.w};
                h1 = half8{(half_t)f2.x, (half_t)f2.y, (half_t)f2.z, (half_t)f2.w,
                           (half_t)f3.x, (half_t)f3.y, (half_t)f3.z, (half_t)f3.w};
            }
            aptr += 32;
        }
        *(half8*)asl = h0;
        *(half8*)(asl + 8) = h1;
        *(half8*)bsl = *(const half8*)bptr;
        *(half8*)(bsl + 8) = *(const half8*)(bptr + 8);
        bptr += 32;
        __syncthreads();

        half8 af[4], bf[4];
#pragma unroll
        for (int i = 0; i < 4; ++i)
            af[i] = *(const half8*)&As[(wr * 64 + i * 16 + rl) * PADK + kg];
#pragma unroll
        for (int j = 0; j < 4; ++j)
            bf[j] = *(const half8*)&Bs[(wc * 64 + j * 16 + rl) * PADK + kg];
#pragma unroll
        for (int i = 0; i < 4; ++i)
#pragma unroll
            for (int j = 0; j < 4; ++j)
                acc[i][j] = __builtin_amdgcn_mfma_f32_16x16x32_f16(af[i], bf[j], acc[i][j], 0, 0, 0);
        __syncthreads();
    }

#pragma unroll
    for (int i = 0; i < 4; ++i) {
        int rbase = m0 + wr * 64 + i * 16 + (lane >> 4) * 4;
#pragma unroll
        for (int r = 0; r < 4; ++r) {
            int row = rbase + r;
            if (row >= Mm) continue;
            if (EPI == 4) {
#pragma unroll
                for (int j = 0; j < 4; j += 2) {
                    int ccbase = n0 + wc * 64 + j * 16;       // multiple of 32
                    int col = (ccbase >> 5) * 16 + rl;        // original a/g column
                    float a = acc[i][j][r];
                    float g = acc[i][j + 1][r];
                    float sg = g / (1.0f + expf(-g));
                    Ch[(size_t)row * (Nn >> 1) + col] = (half_t)(a * sg);
                }
            } else {
#pragma unroll
                for (int j = 0; j < 4; ++j) {
                    int col = n0 + wc * 64 + j * 16 + rl;
                    float vvv = acc[i][j][r];
                    if (EPI == 0) {
                        Cf[(size_t)row * Nn + col] = vvv;
                    } else if (EPI == 1) {
                        if (col < 512) Cf[(size_t)row * 512 + col] = vvv;
                        else C2[(size_t)row * 128 + (col - 512)] = vvv + bias[col - 512];
                    } else if (EPI == 2) {
                        Cf[(size_t)row * Nn + col] += vvv;
                    } else {
                        Ch[(size_t)row * Nn + col] = (half_t)vvv;
                    }
                }
            }
        }
    }
}

// ---------------- rotary + l2norm ----------------
__global__ void qrot_kernel(float* __restrict__ q) {
    int row = blockIdx.x * 4 + (threadIdx.x >> 6);
    int lane = threadIdx.x & 63;
    int pos = (row / kH) % kN;
    float t = q[(size_t)row * kDH + lane];
    float partner = __shfl_xor(t, 1);
    if (lane < kROT) {
        float e = (float)(lane & ~1) / (float)kROT;
        float inv = powf(10000.0f, -e);
        float ang = (float)pos * inv;
        float c = cosf(ang), s = sinf(ang);
        t = (lane & 1) ? fmaf(t, c, partner * s) : fmaf(t, c, -partner * s);
    }
    float ss = wave_sum(t * t);
    q[(size_t)row * kDH + lane] = t * (1.0f / sqrtf(ss));
}

__global__ void krot_kernel(const float* __restrict__ kv, const float* __restrict__ nullkv,
                            float* __restrict__ kk, float* __restrict__ vv) {
    int row = blockIdx.x * 4 + (threadIdx.x >> 6);
    int lane = threadIdx.x & 63;
    int b = row / kNK, jj = row % kNK;
    float tk, tv;
    if (jj == 0) {
        tk = nullkv[lane];
        tv = nullkv[64 + lane];
    } else {
        size_t base = ((size_t)(b * kN + jj - 1)) * 128;
        tk = kv[base + lane];
        tv = kv[base + 64 + lane];
    }
    float partner = __shfl_xor(tk, 1);
    if (jj != 0 && lane < kROT) {
        float e = (float)(lane & ~1) / (float)kROT;
        float inv = powf(10000.0f, -e);
        float ang = (float)(jj - 1) * inv;
        float c = cosf(ang), s = sinf(ang);
        tk = (lane & 1) ? fmaf(tk, c, partner * s) : fmaf(tk, c, -partner * s);
    }
    float ss = wave_sum(tk * tk);
    kk[(size_t)row * kDH + lane] = tk * (1.0f / sqrtf(ss));
    vv[(size_t)row * kDH + lane] = tv;
}

// ---------------- relpos bias table ----------------
__global__ void bias_kernel(const float* __restrict__ emb, float* __restrict__ bias) {
    int idx = blockIdx.x * 256 + threadIdx.x;
    if (idx >= kN * kNK) return;
    int i = idx / kNK, jj = idx % kNK;
    int nn = i - jj; if (nn < 0) nn = 0;
    int bucket;
    if (nn < 16) bucket = nn;
    else {
        float lf = logf((float)nn * (1.0f / 16.0f));
        int vl = 16 + (int)(lf / logf(8.0f) * 16.0f);
        bucket = vl < 31 ? vl : 31;
    }
#pragma unroll
    for (int h = 0; h < kH; ++h)
        bias[((size_t)h * kN + i) * kNK + jj] = emb[bucket * kH + h];
}

// ---------------- attention (fp32) ----------------
__global__ void attn_kernel(const float* __restrict__ q, const float* __restrict__ k,
                            const float* __restrict__ v, const float* __restrict__ bias,
                            float* __restrict__ o) {
    int idx = blockIdx.x;
    int i = idx % kN;
    int bh = idx / kN;
    int h = bh % kH, b = bh / kH;
    int lane = threadIdx.x;
    __shared__ __align__(16) float qs[kDH];
    __shared__ float sc[kNK];

    qs[lane] = q[((size_t)(b * kN + i) * kH + h) * kDH + lane];
    __syncthreads();

    const int jmax = i + 2;
    const float* kb = k + (size_t)b * kNK * kDH;
    const float* bp = bias + ((size_t)h * kN + i) * kNK;

    float mloc = -1e30f;
    for (int j = lane; j < jmax; j += 64) {
        const float4* kr = (const float4*)(kb + (size_t)j * kDH);
        float s = 0.f;
#pragma unroll
        for (int d4 = 0; d4 < 16; ++d4) {
            float4 k4 = kr[d4];
            float4 q4 = *(const float4*)&qs[d4 * 4];
            s += q4.x * k4.x + q4.y * k4.y + q4.z * k4.z + q4.w * k4.w;
        }
        s = 16.0f * s + bp[j];
        sc[j] = s;
        mloc = fmaxf(mloc, s);
    }
    mloc = wave_max(mloc);
    float ssum = 0.f;
    for (int j = lane; j < jmax; j += 64) {
        float p = expf(sc[j] - mloc);
        sc[j] = p;
        ssum += p;
    }
    ssum = wave_sum(ssum);
    __syncthreads();

    float inv = 1.0f / ssum;
    const float* vb = v + (size_t)b * kNK * kDH;
    float a0 = 0.f, a1 = 0.f, a2 = 0.f, a3 = 0.f;
    int j = 0;
    for (; j + 3 < jmax; j += 4) {
        a0 = fmaf(sc[j + 0], vb[(size_t)(j + 0) * kDH + lane], a0);
        a1 = fmaf(sc[j + 1], vb[(size_t)(j + 1) * kDH + lane], a1);
        a2 = fmaf(sc[j + 2], vb[(size_t)(j + 2) * kDH + lane], a2);
        a3 = fmaf(sc[j + 3], vb[(size_t)(j + 3) * kDH + lane], a3);
    }
    for (; j < jmax; ++j) a0 = fmaf(sc[j], vb[(size_t)j * kDH + lane], a0);
    o[((size_t)(b * kN + i) * kH + h) * kDH + lane] = ((a0 + a1) + (a2 + a3)) * inv;
}

}  // namespace

extern "C" void kernel_launch(void* const* d_in, const int* in_sizes, int n_in,
                              void* d_out, int out_size, void* d_ws, size_t ws_size,
                              hipStream_t stream) {
    const float* x_in   = (const float*)d_in[0];
    const float* attn_g = (const float*)d_in[1];
    const float* Wq     = (const float*)d_in[2];
    const float* Wkv    = (const float*)d_in[3];
    const float* bkv    = (const float*)d_in[4];
    const float* nullkv = (const float*)d_in[5];
    const float* Wo     = (const float*)d_in[6];
    const float* out_g  = (const float*)d_in[7];
    const float* ff_g   = (const float*)d_in[8];
    const float* Wff1   = (const float*)d_in[9];
    const float* Wff2   = (const float*)d_in[10];
    const float* emb    = (const float*)d_in[11];
    const float* fin_g  = (const float*)d_in[12];
    const float* Wproj  = (const float*)d_in[13];
    float* out = (float*)d_out;

    char* wsb = (char*)d_ws;
    size_t off = 0;
    auto alloc = [&](size_t bytes) -> void* {
        void* p = wsb + off;
        off += (bytes + 255) & ~(size_t)255;
        return p;
    };
    float*  bx    = (float*)alloc((size_t)kM * kD * 4);
    float*  bxn   = (float*)alloc((size_t)kM * kD * 4);
    float*  bt    = (float*)alloc((size_t)kM * kD * 4);
    float*  bq    = (float*)alloc((size_t)kM * 512 * 4);
    float*  bo    = (float*)alloc((size_t)kM * 512 * 4);
    float*  bkvb  = (float*)alloc((size_t)kM * 128 * 4);
    float*  bk    = (float*)alloc((size_t)kB * kNK * kDH * 4);
    float*  bv    = (float*)alloc((size_t)kB * kNK * kDH * 4);
    float*  bbias = (float*)alloc((size_t)kH * kN * kNK * 4);
    half_t* bg    = (half_t*)alloc((size_t)kM * kFF * 2);      // a*silu(g), fp16
    half_t* WqkvT = (half_t*)alloc((size_t)640 * kD * 2);      // per-layer
    half_t* WoT   = (half_t*)alloc((size_t)kD * 512 * 2);
    half_t* Wff1T = (half_t*)alloc((size_t)2 * kFF * kD * 2);  // interleaved a/g
    half_t* Wff2T = (half_t*)alloc((size_t)kD * kFF * 2);

    hipMemcpyAsync(bx, x_in, (size_t)kM * kD * 4, hipMemcpyDeviceToDevice, stream);
    bias_kernel<<<(kN * kNK + 255) / 256, 256, 0, stream>>>(emb, bbias);

    const int mt = (kM + 127) / 128;  // 33 row tiles

    for (int l = 0; l < kL; ++l) {
        // convert this layer's weights (fp32 [K][N] -> fp16 B^T [N][K])
        tcvt_kernel<0><<<dim3(512 / 32, kD / 32), 256, 0, stream>>>(
            Wq + (size_t)l * kD * 512, WqkvT, kD, 512, kD, 0);
        tcvt_kernel<0><<<dim3(128 / 32, kD / 32), 256, 0, stream>>>(
            Wkv + (size_t)l * kD * 128, WqkvT, kD, 128, kD, 512);
        tcvt_kernel<0><<<dim3(kD / 32, 512 / 32), 256, 0, stream>>>(
            Wo + (size_t)l * 512 * kD, WoT, 512, kD, 512, 0);
        tcvt_kernel<1><<<dim3(2 * kFF / 32, kD / 32), 256, 0, stream>>>(
            Wff1 + (size_t)l * kD * 2 * kFF, Wff1T, kD, 2 * kFF, kD, 0);
        tcvt_kernel<0><<<dim3(kD / 32, kFF / 32), 256, 0, stream>>>(
            Wff2 + (size_t)l * kFF * kD, Wff2T, kFF, kD, kFF, 0);

        ln_kernel<0><<<kM, 256, 0, stream>>>(bx, attn_g + (size_t)l * kD, bxn);
        mm_kernel<0, 1><<<dim3(640 / 128, mt), 256, 0, stream>>>(
            bxn, nullptr, WqkvT, bq, nullptr, bkvb, bkv + (size_t)l * 128, kM, 640, kD);
        qrot_kernel<<<kM * kH / 4, 256, 0, stream>>>(bq);
        krot_kernel<<<kB * kNK / 4, 256, 0, stream>>>(bkvb, nullkv + (size_t)l * 128, bk, bv);
        attn_kernel<<<kB * kH * kN, 64, 0, stream>>>(bq, bk, bv, bbias, bo);
        mm_kernel<0, 0><<<dim3(kD / 128, mt), 256, 0, stream>>>(
            bo, nullptr, WoT, bt, nullptr, nullptr, nullptr, kM, kD, 512);
        ln_kernel<1><<<kM, 256, 0, stream>>>(bt, out_g + (size_t)l * kD, bx);
        ln_kernel<0><<<kM, 256, 0, stream>>>(bx, ff_g + (size_t)l * kD, bxn);
        mm_kernel<0, 4><<<dim3(2 * kFF / 128, mt), 256, 0, stream>>>(
            bxn, nullptr, Wff1T, nullptr, bg, nullptr, nullptr, kM, 2 * kFF, kD);
        mm_kernel<1, 2><<<dim3(kD / 128, mt), 256, 0, stream>>>(
            nullptr, bg, Wff2T, bx, nullptr, nullptr, nullptr, kM, kD, kFF);
    }

    ln_kernel<2><<<kM, 256, 0, stream>>>(bx, fin_g, bxn);
    // reuse Wff1T region for Wproj^T (last FF1 GEMM already consumed it)
    tcvt_kernel<0><<<dim3(kD / 32, kD / 32), 256, 0, stream>>>(Wproj, (half_t*)Wff1T, kD, kD, kD, 0);
    mm_kernel<0, 0><<<dim3(kD / 128, mt), 256, 0, stream>>>(
        bxn, nullptr, (half_t*)Wff1T, out, nullptr, nullptr, nullptr, kM, kD, kD);
}

// Round 6
// 1996.717 us; speedup vs baseline: 5.1921x; 1.6447x over previous
//
#include <hip/hip_runtime.h>
#include <cmath>

namespace {

constexpr int kB = 8, kN = 515, kD = 1024, kH = 8, kDH = 64, kL = 4;
constexpr int kFF = 4096, kROT = 32;
constexpr int kNK = kN + 1;        // 516 keys (null + N)
constexpr int kNKP = 576;          // padded keys (9 tiles of 64)
constexpr int kM = kB * kN;        // 4120 token rows
constexpr float kEPS = 1e-5f;

typedef _Float16 half_t;
typedef _Float16 half8 __attribute__((ext_vector_type(8)));
typedef float f32x4 __attribute__((ext_vector_type(4)));

__device__ __forceinline__ float wave_sum(float v) {
#pragma unroll
    for (int o = 32; o > 0; o >>= 1) v += __shfl_xor(v, o);
    return v;
}
__device__ __forceinline__ float wave_max(float v) {
#pragma unroll
    for (int o = 32; o > 0; o >>= 1) v = fmaxf(v, __shfl_xor(v, o));
    return v;
}

// ---------------- LayerNorm family ----------------
template<int MODE>  // 0: out=LN(in)*g   1: out+=LN(in)*g   2: out=LN(in/max)*g
__global__ void ln_kernel(const float* __restrict__ in, const float* __restrict__ g,
                          float* __restrict__ out) {
    int row = blockIdx.x;
    const float4* inr = (const float4*)(in + (size_t)row * kD);
    float4 v = inr[threadIdx.x];
    __shared__ float red[4];
    int lane = threadIdx.x & 63, wid = threadIdx.x >> 6;

    if (MODE == 2) {
        float mx = fmaxf(fmaxf(v.x, v.y), fmaxf(v.z, v.w));
        mx = wave_max(mx);
        if (lane == 0) red[wid] = mx;
        __syncthreads();
        mx = fmaxf(fmaxf(red[0], red[1]), fmaxf(red[2], red[3]));
        __syncthreads();
        float inv = 1.0f / mx;
        v.x *= inv; v.y *= inv; v.z *= inv; v.w *= inv;
    }

    float s = v.x + v.y + v.z + v.w;
    s = wave_sum(s);
    if (lane == 0) red[wid] = s;
    __syncthreads();
    float mean = (red[0] + red[1] + red[2] + red[3]) * (1.0f / kD);
    __syncthreads();

    float dx = v.x - mean, dy = v.y - mean, dz = v.z - mean, dw = v.w - mean;
    float ss = dx * dx + dy * dy + dz * dz + dw * dw;
    ss = wave_sum(ss);
    if (lane == 0) red[wid] = ss;
    __syncthreads();
    float var = (red[0] + red[1] + red[2] + red[3]) * (1.0f / kD);
    float r = 1.0f / sqrtf(var + kEPS);

    float4 g4 = ((const float4*)g)[threadIdx.x];
    float4 o4 = make_float4(dx * r * g4.x, dy * r * g4.y, dz * r * g4.z, dw * r * g4.w);
    float4* op = (float4*)(out + (size_t)row * kD);
    if (MODE == 1) {
        float4 c = op[threadIdx.x];
        o4.x += c.x; o4.y += c.y; o4.z += c.z; o4.w += c.w;
    }
    op[threadIdx.x] = o4;
}

// ------- weight transpose+convert: W[k][n] f32 -> Wt[row'(n)][k] f16 -------
// ILV=0: row' = rowOff + n.
// ILV=1 (Wff1 a/g interleave): n<FF: row' = (n>>4)*32 + (n&15);
//                              n>=FF: c=n-FF, row' = (c>>4)*32 + 16 + (c&15).
template<int ILV>
__global__ void tcvt_kernel(const float* __restrict__ src, half_t* __restrict__ dst,
                            int K, int N, int pitch, int rowOff) {
    __shared__ float tile[32][33];
    int tx = threadIdx.x & 31, ty = threadIdx.x >> 5;  // 256 thr: ty 0..7
    int n0 = blockIdx.x * 32, k0 = blockIdx.y * 32;
#pragma unroll
    for (int j = 0; j < 4; ++j)
        tile[ty + 8 * j][tx] = src[(size_t)(k0 + ty + 8 * j) * N + n0 + tx];
    __syncthreads();
#pragma unroll
    for (int j = 0; j < 4; ++j) {
        int n = n0 + ty + 8 * j;
        int rowp;
        if (ILV == 0) {
            rowp = rowOff + n;
        } else {
            if (n < kFF) rowp = ((n >> 4) << 5) + (n & 15);
            else { int c = n - kFF; rowp = ((c >> 4) << 5) + 16 + (c & 15); }
        }
        dst[(size_t)rowp * pitch + k0 + tx] = (half_t)tile[tx][ty + 8 * j];
    }
}

// ---------------- fp16 MFMA GEMM ----------------
// C[M,N] = A[M,K] @ Bt[N,K]^T.  128x128 tile, BK=32, 4 waves (2x2), wave=64x64 (4x4 frags).
// EPI: 0 f32 store, 1 qkv split (+bias on kv), 2 f32 +=, 3 f16 store,
//      4 glu: interleaved a/g cols -> Ch[row][c] = a*silu(g), Ch pitch Nn/2
template<int AF16, int EPI>
__global__ __launch_bounds__(256)
void mm_kernel(const float* __restrict__ Af, const half_t* __restrict__ Ah,
               const half_t* __restrict__ Bt,
               float* __restrict__ Cf, half_t* __restrict__ Ch,
               float* __restrict__ C2, const float* __restrict__ bias,
               int Mm, int Nn, int Kk) {
    constexpr int PADK = 40;  // 32 f16 + 8 pad -> 80B row stride
    __shared__ half_t As[128 * PADK];
    __shared__ half_t Bs[128 * PADK];
    const int m0 = blockIdx.y * 128, n0 = blockIdx.x * 128;
    const int t = threadIdx.x, lane = t & 63, wid = t >> 6;
    const int wr = wid >> 1, wc = wid & 1;
    const int srow = t >> 1, skh = (t & 1) * 16;

    f32x4 acc[4][4] = {};

    const int arow = m0 + srow;
    const bool aval = arow < Mm;
    const float*  aptr  = Af + (size_t)arow * Kk + skh;
    const half_t* ahptr = Ah + (size_t)arow * Kk + skh;
    const half_t* bptr  = Bt + (size_t)(n0 + srow) * Kk + skh;
    half_t* asl = &As[srow * PADK + skh];
    half_t* bsl = &Bs[srow * PADK + skh];

    const int kg = (lane >> 4) * 8;   // k-offset of this lane's fragment
    const int rl = lane & 15;

    for (int k0 = 0; k0 < Kk; k0 += 32) {
        half8 h0 = {0, 0, 0, 0, 0, 0, 0, 0}, h1 = {0, 0, 0, 0, 0, 0, 0, 0};
        if (AF16) {
            if (aval) { h0 = *(const half8*)ahptr; h1 = *(const half8*)(ahptr + 8); }
            ahptr += 32;
        } else {
            if (aval) {
                const float4* a4 = (const float4*)aptr;
                float4 f0 = a4[0], f1 = a4[1], f2 = a4[2], f3 = a4[3];
                h0 = half8{(half_t)f0.x, (half_t)f0.y, (half_t)f0.z, (half_t)f0.w,
                           (half_t)f1.x, (half_t)f1.y, (half_t)f1.z, (half_t)f1.w};
                h1 = half8{(half_t)f2.x, (half_t)f2.y, (half_t)f2.z, (half_t)f2.w,
                           (half_t)f3.x, (half_t)f3.y, (half_t)f3.z, (half_t)f3.w};
            }
            aptr += 32;
        }
        *(half8*)asl = h0;
        *(half8*)(asl + 8) = h1;
        *(half8*)bsl = *(const half8*)bptr;
        *(half8*)(bsl + 8) = *(const half8*)(bptr + 8);
        bptr += 32;
        __syncthreads();

        half8 af[4], bf[4];
#pragma unroll
        for (int i = 0; i < 4; ++i)
            af[i] = *(const half8*)&As[(wr * 64 + i * 16 + rl) * PADK + kg];
#pragma unroll
        for (int j = 0; j < 4; ++j)
            bf[j] = *(const half8*)&Bs[(wc * 64 + j * 16 + rl) * PADK + kg];
#pragma unroll
        for (int i = 0; i < 4; ++i)
#pragma unroll
            for (int j = 0; j < 4; ++j)
                acc[i][j] = __builtin_amdgcn_mfma_f32_16x16x32_f16(af[i], bf[j], acc[i][j], 0, 0, 0);
        __syncthreads();
    }

#pragma unroll
    for (int i = 0; i < 4; ++i) {
        int rbase = m0 + wr * 64 + i * 16 + (lane >> 4) * 4;
#pragma unroll
        for (int r = 0; r < 4; ++r) {
            int row = rbase + r;
            if (row >= Mm) continue;
            if (EPI == 4) {
#pragma unroll
                for (int j = 0; j < 4; j += 2) {
                    int ccbase = n0 + wc * 64 + j * 16;       // multiple of 32
                    int col = (ccbase >> 5) * 16 + rl;        // original a/g column
                    float a = acc[i][j][r];
                    float g = acc[i][j + 1][r];
                    float sg = g / (1.0f + expf(-g));
                    Ch[(size_t)row * (Nn >> 1) + col] = (half_t)(a * sg);
                }
            } else {
#pragma unroll
                for (int j = 0; j < 4; ++j) {
                    int col = n0 + wc * 64 + j * 16 + rl;
                    float vvv = acc[i][j][r];
                    if (EPI == 0) {
                        Cf[(size_t)row * Nn + col] = vvv;
                    } else if (EPI == 1) {
                        if (col < 512) Cf[(size_t)row * 512 + col] = vvv;
                        else C2[(size_t)row * 128 + (col - 512)] = vvv + bias[col - 512];
                    } else if (EPI == 2) {
                        Cf[(size_t)row * Nn + col] += vvv;
                    } else {
                        Ch[(size_t)row * Nn + col] = (half_t)vvv;
                    }
                }
            }
        }
    }
}

// ---------------- rotary + l2norm -> fp16 (q-hat * 4) ----------------
// reads bq fp32 rows [(b*kN+n)*kH + h][64], writes Qh [b][h][576][64] fp16
__global__ void qrot_kernel(const float* __restrict__ q, half_t* __restrict__ Qh) {
    int row = blockIdx.x * 4 + (threadIdx.x >> 6);
    int lane = threadIdx.x & 63;
    int h = row % kH;
    int bn = row / kH;
    int b = bn / kN, n = bn % kN;
    float t = q[(size_t)row * kDH + lane];
    float partner = __shfl_xor(t, 1);
    if (lane < kROT) {
        float e = (float)(lane & ~1) / (float)kROT;
        float inv = powf(10000.0f, -e);
        float ang = (float)n * inv;
        float c = cosf(ang), s = sinf(ang);
        t = (lane & 1) ? fmaf(t, c, partner * s) : fmaf(t, c, -partner * s);
    }
    float ss = wave_sum(t * t);
    float sc = 4.0f / sqrtf(ss);
    Qh[(((size_t)b * kH + h) * kNKP + n) * kDH + lane] = (half_t)(t * sc);
}

// kv fp32 [(b,n)][128] -> Kh [b][576][64] fp16 (k-hat*4, zero pad), VTh [b][64][576] fp16
__global__ void krot_kernel(const float* __restrict__ kv, const float* __restrict__ nullkv,
                            half_t* __restrict__ Kh, half_t* __restrict__ VTh) {
    int row = blockIdx.x * 4 + (threadIdx.x >> 6);   // b*576 + jj
    int lane = threadIdx.x & 63;
    int b = row / kNKP, jj = row % kNKP;
    float tk = 0.f, tv = 0.f;
    if (jj == 0) {
        tk = nullkv[lane];
        tv = nullkv[64 + lane];
    } else if (jj < kNK) {
        size_t base = ((size_t)(b * kN + jj - 1)) * 128;
        tk = kv[base + lane];
        tv = kv[base + 64 + lane];
    }
    float partner = __shfl_xor(tk, 1);
    if (jj != 0 && jj < kNK && lane < kROT) {
        float e = (float)(lane & ~1) / (float)kROT;
        float inv = powf(10000.0f, -e);
        float ang = (float)(jj - 1) * inv;
        float c = cosf(ang), s = sinf(ang);
        tk = (lane & 1) ? fmaf(tk, c, partner * s) : fmaf(tk, c, -partner * s);
    }
    float ss = wave_sum(tk * tk);
    float sc = (jj < kNK) ? 4.0f / sqrtf(ss) : 0.f;
    Kh[(size_t)row * kDH + lane] = (half_t)(tk * sc);
    VTh[((size_t)b * kDH + lane) * kNKP + jj] = (half_t)tv;
}

// ---------------- relpos bias delta table: db[h][idx], idx = i-j+1 in [0,515] -------
__global__ void dbias_kernel(const float* __restrict__ emb, float* __restrict__ db) {
    int t = blockIdx.x * 256 + threadIdx.x;
    if (t >= kH * 516) return;
    int h = t / 516, idx = t % 516;
    int nn = idx - 1; if (nn < 0) nn = 0;
    int bucket;
    if (nn < 16) bucket = nn;
    else {
        float lf = logf((float)nn * (1.0f / 16.0f));
        int vl = 16 + (int)(lf / logf(8.0f) * 16.0f);
        bucket = vl < 31 ? vl : 31;
    }
    db[t] = emb[bucket * kH + h];
}

// ---------------- MFMA flash attention ----------------
// grid (qt=9, h=8, b=8), 256 threads = 4 waves, wave = 16 queries.
// Qh [b][h][576][64], Kh [b][576][64], VTh [b][64][576] all fp16 (q,k scaled by 4).
// o fp32 [(b*kN+n)][h*64+d]
__global__ __launch_bounds__(256)
void fattn_kernel(const half_t* __restrict__ Qh, const half_t* __restrict__ Kh,
                  const half_t* __restrict__ VTh, const float* __restrict__ dbias,
                  float* __restrict__ o) {
    const int qt = blockIdx.x, h = blockIdx.y, b = blockIdx.z;
    const int t = threadIdx.x, lane = t & 63, w = t >> 6;
    const int rl = lane & 15, g = lane >> 4;
    const int q0 = qt * 64, qw0 = q0 + w * 16;

    __shared__ half_t Ps[4][16][72];
    __shared__ float db[520];
    for (int i = t; i < 516; i += 256) db[i] = dbias[h * 516 + i];
    __syncthreads();

    // Q fragments (row = rl, k-offset = g*8), loop-invariant
    const half_t* qbase = Qh + (((size_t)b * kH + h) * kNKP + qw0 + rl) * kDH;
    half8 qa0 = *(const half8*)(qbase + g * 8);
    half8 qa1 = *(const half8*)(qbase + 32 + g * 8);

    float m[4] = {-1e30f, -1e30f, -1e30f, -1e30f};
    float l[4] = {0.f, 0.f, 0.f, 0.f};
    f32x4 Oa[4] = {};

    const int wktiles = min((qw0 + 16) / 64 + 1, kNKP / 64);

    for (int kt = 0; kt < wktiles; ++kt) {
        const int jt = kt * 64;
        // QK^T: 4 frags of 16 keys
        f32x4 sc[4];
#pragma unroll
        for (int f = 0; f < 4; ++f) {
            const half_t* kp = Kh + ((size_t)b * kNKP + jt + f * 16 + rl) * kDH + g * 8;
            half8 kb0 = *(const half8*)kp;
            half8 kb1 = *(const half8*)(kp + 32);
            f32x4 a = {};
            a = __builtin_amdgcn_mfma_f32_16x16x32_f16(qa0, kb0, a, 0, 0, 0);
            a = __builtin_amdgcn_mfma_f32_16x16x32_f16(qa1, kb1, a, 0, 0, 0);
            sc[f] = a;
        }
        // bias + causal mask + tile row-max
        float tm[4] = {-1e30f, -1e30f, -1e30f, -1e30f};
#pragma unroll
        for (int f = 0; f < 4; ++f) {
            int jb = jt + f * 16 + rl;
#pragma unroll
            for (int r = 0; r < 4; ++r) {
                int qq = qw0 + 4 * g + r;
                int idx = qq - jb + 1;
                int ic = idx < 0 ? 0 : (idx > 515 ? 515 : idx);
                float s = sc[f][r] + db[ic];
                s = (idx < 0) ? -1e30f : s;
                sc[f][r] = s;
                tm[r] = fmaxf(tm[r], s);
            }
        }
#pragma unroll
        for (int off = 1; off < 16; off <<= 1)
#pragma unroll
            for (int r = 0; r < 4; ++r) tm[r] = fmaxf(tm[r], __shfl_xor(tm[r], off));
        // online softmax update
        float scal[4], tsum[4];
#pragma unroll
        for (int r = 0; r < 4; ++r) {
            float nm = fmaxf(m[r], tm[r]);
            scal[r] = __expf(m[r] - nm);
            m[r] = nm;
            tsum[r] = 0.f;
        }
#pragma unroll
        for (int f = 0; f < 4; ++f)
#pragma unroll
            for (int r = 0; r < 4; ++r) {
                float p = __expf(sc[f][r] - m[r]);
                tsum[r] += p;
                Ps[w][4 * g + r][f * 16 + rl] = (half_t)p;
            }
#pragma unroll
        for (int r = 0; r < 4; ++r) l[r] = l[r] * scal[r] + tsum[r];
#pragma unroll
        for (int fd = 0; fd < 4; ++fd)
#pragma unroll
            for (int r = 0; r < 4; ++r) Oa[fd][r] *= scal[r];
        // P A-frags from wave-private LDS
        half8 pa0 = *(const half8*)&Ps[w][rl][g * 8];
        half8 pa1 = *(const half8*)&Ps[w][rl][32 + g * 8];
        // PV: O += P @ V  (B-frag rows = d from VTh)
#pragma unroll
        for (int fd = 0; fd < 4; ++fd) {
            const half_t* vp = VTh + ((size_t)b * kDH + fd * 16 + rl) * kNKP + jt + g * 8;
            half8 vb0 = *(const half8*)vp;
            half8 vb1 = *(const half8*)(vp + 32);
            Oa[fd] = __builtin_amdgcn_mfma_f32_16x16x32_f16(pa0, vb0, Oa[fd], 0, 0, 0);
            Oa[fd] = __builtin_amdgcn_mfma_f32_16x16x32_f16(pa1, vb1, Oa[fd], 0, 0, 0);
        }
    }

    // final: reduce l across the 16-lane col group, store O / l
    float inv[4];
#pragma unroll
    for (int r = 0; r < 4; ++r) {
        float L = l[r];
#pragma unroll
        for (int off = 1; off < 16; off <<= 1) L += __shfl_xor(L, off);
        inv[r] = 1.0f / L;
    }
#pragma unroll
    for (int fd = 0; fd < 4; ++fd)
#pragma unroll
        for (int r = 0; r < 4; ++r) {
            int qq = qw0 + 4 * g + r;
            if (qq < kN)
                o[((size_t)(b * kN + qq) * kH + h) * kDH + fd * 16 + rl] = Oa[fd][r] * inv[r];
        }
}

}  // namespace

extern "C" void kernel_launch(void* const* d_in, const int* in_sizes, int n_in,
                              void* d_out, int out_size, void* d_ws, size_t ws_size,
                              hipStream_t stream) {
    const float* x_in   = (const float*)d_in[0];
    const float* attn_g = (const float*)d_in[1];
    const float* Wq     = (const float*)d_in[2];
    const float* Wkv    = (const float*)d_in[3];
    const float* bkv    = (const float*)d_in[4];
    const float* nullkv = (const float*)d_in[5];
    const float* Wo     = (const float*)d_in[6];
    const float* out_g  = (const float*)d_in[7];
    const float* ff_g   = (const float*)d_in[8];
    const float* Wff1   = (const float*)d_in[9];
    const float* Wff2   = (const float*)d_in[10];
    const float* emb    = (const float*)d_in[11];
    const float* fin_g  = (const float*)d_in[12];
    const float* Wproj  = (const float*)d_in[13];
    float* out = (float*)d_out;

    char* wsb = (char*)d_ws;
    size_t off = 0;
    auto alloc = [&](size_t bytes) -> void* {
        void* p = wsb + off;
        off += (bytes + 255) & ~(size_t)255;
        return p;
    };
    float*  bx    = (float*)alloc((size_t)kM * kD * 4);
    float*  bxn   = (float*)alloc((size_t)kM * kD * 4);
    float*  bt    = (float*)alloc((size_t)kM * kD * 4);
    float*  bq    = (float*)alloc((size_t)kM * 512 * 4);
    float*  bo    = (float*)alloc((size_t)kM * 512 * 4);
    float*  bkvb  = (float*)alloc((size_t)kM * 128 * 4);
    half_t* Qh    = (half_t*)alloc((size_t)kB * kH * kNKP * kDH * 2);
    half_t* Kh    = (half_t*)alloc((size_t)kB * kNKP * kDH * 2);
    half_t* VTh   = (half_t*)alloc((size_t)kB * kDH * kNKP * 2);
    float*  dbias = (float*)alloc((size_t)kH * 516 * 4);
    half_t* bg    = (half_t*)alloc((size_t)kM * kFF * 2);      // a*silu(g), fp16
    half_t* WqkvT = (half_t*)alloc((size_t)640 * kD * 2);      // per-layer
    half_t* WoT   = (half_t*)alloc((size_t)kD * 512 * 2);
    half_t* Wff1T = (half_t*)alloc((size_t)2 * kFF * kD * 2);  // interleaved a/g
    half_t* Wff2T = (half_t*)alloc((size_t)kD * kFF * 2);

    hipMemcpyAsync(bx, x_in, (size_t)kM * kD * 4, hipMemcpyDeviceToDevice, stream);
    dbias_kernel<<<(kH * 516 + 255) / 256, 256, 0, stream>>>(emb, dbias);

    const int mt = (kM + 127) / 128;  // 33 row tiles

    for (int l = 0; l < kL; ++l) {
        // convert this layer's weights (fp32 [K][N] -> fp16 B^T [N][K])
        tcvt_kernel<0><<<dim3(512 / 32, kD / 32), 256, 0, stream>>>(
            Wq + (size_t)l * kD * 512, WqkvT, kD, 512, kD, 0);
        tcvt_kernel<0><<<dim3(128 / 32, kD / 32), 256, 0, stream>>>(
            Wkv + (size_t)l * kD * 128, WqkvT, kD, 128, kD, 512);
        tcvt_kernel<0><<<dim3(kD / 32, 512 / 32), 256, 0, stream>>>(
            Wo + (size_t)l * 512 * kD, WoT, 512, kD, 512, 0);
        tcvt_kernel<1><<<dim3(2 * kFF / 32, kD / 32), 256, 0, stream>>>(
            Wff1 + (size_t)l * kD * 2 * kFF, Wff1T, kD, 2 * kFF, kD, 0);
        tcvt_kernel<0><<<dim3(kD / 32, kFF / 32), 256, 0, stream>>>(
            Wff2 + (size_t)l * kFF * kD, Wff2T, kFF, kD, kFF, 0);

        ln_kernel<0><<<kM, 256, 0, stream>>>(bx, attn_g + (size_t)l * kD, bxn);
        mm_kernel<0, 1><<<dim3(640 / 128, mt), 256, 0, stream>>>(
            bxn, nullptr, WqkvT, bq, nullptr, bkvb, bkv + (size_t)l * 128, kM, 640, kD);
        qrot_kernel<<<kM * kH / 4, 256, 0, stream>>>(bq, Qh);
        krot_kernel<<<kB * kNKP / 4, 256, 0, stream>>>(bkvb, nullkv + (size_t)l * 128, Kh, VTh);
        fattn_kernel<<<dim3(kNKP / 64, kH, kB), 256, 0, stream>>>(Qh, Kh, VTh, dbias, bo);
        mm_kernel<0, 0><<<dim3(kD / 128, mt), 256, 0, stream>>>(
            bo, nullptr, WoT, bt, nullptr, nullptr, nullptr, kM, kD, 512);
        ln_kernel<1><<<kM, 256, 0, stream>>>(bt, out_g + (size_t)l * kD, bx);
        ln_kernel<0><<<kM, 256, 0, stream>>>(bx, ff_g + (size_t)l * kD, bxn);
        mm_kernel<0, 4><<<dim3(2 * kFF / 128, mt), 256, 0, stream>>>(
            bxn, nullptr, Wff1T, nullptr, bg, nullptr, nullptr, kM, 2 * kFF, kD);
        mm_kernel<1, 2><<<dim3(kD / 128, mt), 256, 0, stream>>>(
            nullptr, bg, Wff2T, bx, nullptr, nullptr, nullptr, kM, kD, kFF);
    }

    ln_kernel<2><<<kM, 256, 0, stream>>>(bx, fin_g, bxn);
    // reuse Wff1T region for Wproj^T (last FF1 GEMM already consumed it)
    tcvt_kernel<0><<<dim3(kD / 32, kD / 32), 256, 0, stream>>>(Wproj, (half_t*)Wff1T, kD, kD, kD, 0);
    mm_kernel<0, 0><<<dim3(kD / 128, mt), 256, 0, stream>>>(
        bxn, nullptr, (half_t*)Wff1T, out, nullptr, nullptr, nullptr, kM, kD, kD);
}

// Round 8
// 1744.666 us; speedup vs baseline: 5.9422x; 1.1445x over previous
//
#include <hip/hip_runtime.h>
#include <cmath>

namespace {

constexpr int kB = 8, kN = 515, kD = 1024, kH = 8, kDH = 64, kL = 4;
constexpr int kFF = 4096, kROT = 32;
constexpr int kNK = kN + 1;        // 516 keys (null + N)
constexpr int kNKP = 576;          // padded keys (9 tiles of 64)
constexpr int kM = kB * kN;        // 4120 token rows
constexpr float kEPS = 1e-5f;

typedef _Float16 half_t;
typedef _Float16 half8 __attribute__((ext_vector_type(8)));
typedef _Float16 half4 __attribute__((ext_vector_type(4)));
typedef float f32x4 __attribute__((ext_vector_type(4)));

__device__ __forceinline__ float wave_sum(float v) {
#pragma unroll
    for (int o = 32; o > 0; o >>= 1) v += __shfl_xor(v, o);
    return v;
}
__device__ __forceinline__ float wave_max(float v) {
#pragma unroll
    for (int o = 32; o > 0; o >>= 1) v = fmaxf(v, __shfl_xor(v, o));
    return v;
}

__device__ __forceinline__ void gload_lds16(const half_t* g, half_t* l) {
    __builtin_amdgcn_global_load_lds(
        (const __attribute__((address_space(1))) void*)g,
        (__attribute__((address_space(3))) void*)l, 16, 0, 0);
}

// ---------------- LayerNorm -> fp16 ----------------
template<int MODE>  // 0: out=LN(in)*g   2: out=LN(in/max)*g (stable)
__global__ void ln_kernel(const float* __restrict__ in, const float* __restrict__ g,
                          half_t* __restrict__ out) {
    int row = blockIdx.x;
    float4 v = ((const float4*)(in + (size_t)row * kD))[threadIdx.x];
    __shared__ float red[4];
    int lane = threadIdx.x & 63, wid = threadIdx.x >> 6;

    if (MODE == 2) {
        float mx = fmaxf(fmaxf(v.x, v.y), fmaxf(v.z, v.w));
        mx = wave_max(mx);
        if (lane == 0) red[wid] = mx;
        __syncthreads();
        mx = fmaxf(fmaxf(red[0], red[1]), fmaxf(red[2], red[3]));
        __syncthreads();
        float inv = 1.0f / mx;
        v.x *= inv; v.y *= inv; v.z *= inv; v.w *= inv;
    }

    float s = v.x + v.y + v.z + v.w;
    s = wave_sum(s);
    if (lane == 0) red[wid] = s;
    __syncthreads();
    float mean = (red[0] + red[1] + red[2] + red[3]) * (1.0f / kD);
    __syncthreads();

    float dx = v.x - mean, dy = v.y - mean, dz = v.z - mean, dw = v.w - mean;
    float ss = dx * dx + dy * dy + dz * dz + dw * dw;
    ss = wave_sum(ss);
    if (lane == 0) red[wid] = ss;
    __syncthreads();
    float var = (red[0] + red[1] + red[2] + red[3]) * (1.0f / kD);
    float r = 1.0f / sqrtf(var + kEPS);

    float4 g4 = ((const float4*)g)[threadIdx.x];
    half4 o4 = {(half_t)(dx * r * g4.x), (half_t)(dy * r * g4.y),
                (half_t)(dz * r * g4.z), (half_t)(dw * r * g4.w)};
    ((half4*)(out + (size_t)row * kD))[threadIdx.x] = o4;
}

// ---- fused: res += LN(in)*g1 ; outh = (half)(LN(res)*g2) ----
__global__ void ln_add_ln_kernel(const float* __restrict__ in, const float* __restrict__ g1,
                                 float* __restrict__ res, const float* __restrict__ g2,
                                 half_t* __restrict__ outh) {
    int row = blockIdx.x;
    float4 v = ((const float4*)(in + (size_t)row * kD))[threadIdx.x];
    __shared__ float red[4];
    int lane = threadIdx.x & 63, wid = threadIdx.x >> 6;

    float s = v.x + v.y + v.z + v.w;
    s = wave_sum(s);
    if (lane == 0) red[wid] = s;
    __syncthreads();
    float mean = (red[0] + red[1] + red[2] + red[3]) * (1.0f / kD);
    __syncthreads();
    float dx = v.x - mean, dy = v.y - mean, dz = v.z - mean, dw = v.w - mean;
    float ss = dx * dx + dy * dy + dz * dz + dw * dw;
    ss = wave_sum(ss);
    if (lane == 0) red[wid] = ss;
    __syncthreads();
    float var = (red[0] + red[1] + red[2] + red[3]) * (1.0f / kD);
    float r = 1.0f / sqrtf(var + kEPS);

    float4 g4 = ((const float4*)g1)[threadIdx.x];
    float4 res4 = ((const float4*)(res + (size_t)row * kD))[threadIdx.x];
    float4 nv = make_float4(res4.x + dx * r * g4.x, res4.y + dy * r * g4.y,
                            res4.z + dz * r * g4.z, res4.w + dw * r * g4.w);
    ((float4*)(res + (size_t)row * kD))[threadIdx.x] = nv;
    __syncthreads();

    // second LN over nv
    float s2 = nv.x + nv.y + nv.z + nv.w;
    s2 = wave_sum(s2);
    if (lane == 0) red[wid] = s2;
    __syncthreads();
    float mean2 = (red[0] + red[1] + red[2] + red[3]) * (1.0f / kD);
    __syncthreads();
    float ex = nv.x - mean2, ey = nv.y - mean2, ez = nv.z - mean2, ew = nv.w - mean2;
    float ss2 = ex * ex + ey * ey + ez * ez + ew * ew;
    ss2 = wave_sum(ss2);
    if (lane == 0) red[wid] = ss2;
    __syncthreads();
    float var2 = (red[0] + red[1] + red[2] + red[3]) * (1.0f / kD);
    float r2 = 1.0f / sqrtf(var2 + kEPS);

    float4 h4 = ((const float4*)g2)[threadIdx.x];
    half4 o4 = {(half_t)(ex * r2 * h4.x), (half_t)(ey * r2 * h4.y),
                (half_t)(ez * r2 * h4.z), (half_t)(ew * r2 * h4.w)};
    ((half4*)(outh + (size_t)row * kD))[threadIdx.x] = o4;
}

// ------- weight transpose+convert: W[k][n] f32 -> Wt[row'(n)][k] f16 -------
// ILV=0: row' = rowOff + n.
// ILV=1 (Wff1 a/g interleave): n<FF: row' = (n>>4)*32 + (n&15);
//                              n>=FF: c=n-FF, row' = (c>>4)*32 + 16 + (c&15).
template<int ILV>
__global__ void tcvt_kernel(const float* __restrict__ src, half_t* __restrict__ dst,
                            int K, int N, int pitch, int rowOff) {
    __shared__ float tile[32][33];
    int tx = threadIdx.x & 31, ty = threadIdx.x >> 5;  // 256 thr: ty 0..7
    int n0 = blockIdx.x * 32, k0 = blockIdx.y * 32;
#pragma unroll
    for (int j = 0; j < 4; ++j)
        tile[ty + 8 * j][tx] = src[(size_t)(k0 + ty + 8 * j) * N + n0 + tx];
    __syncthreads();
#pragma unroll
    for (int j = 0; j < 4; ++j) {
        int n = n0 + ty + 8 * j;
        int rowp;
        if (ILV == 0) {
            rowp = rowOff + n;
        } else {
            if (n < kFF) rowp = ((n >> 4) << 5) + (n & 15);
            else { int c = n - kFF; rowp = ((c >> 4) << 5) + 16 + (c & 15); }
        }
        dst[(size_t)rowp * pitch + k0 + tx] = (half_t)tile[tx][ty + 8 * j];
    }
}

// ---------------- fp16 MFMA GEMM (global_load_lds staging) ----------------
// C[M,N] = A[M,K] @ Bt[N,K]^T.  128x128 tile, BK=32, 4 waves (2x2), wave=64x64.
// EPI: 0 f32 store, 1 qkv split (+bias on kv), 2 f32 +=,
//      4 glu: interleaved a/g cols -> Ch[row][c] = a*silu(g), Ch pitch Nn/2
template<int EPI>
__global__ __launch_bounds__(256)
void mm_kernel(const half_t* __restrict__ A, const half_t* __restrict__ Bt,
               float* __restrict__ Cf, half_t* __restrict__ Ch,
               float* __restrict__ C2, const float* __restrict__ bias,
               int Mm, int Nn, int Kk) {
    __shared__ half_t As[128 * 32];
    __shared__ half_t Bs[128 * 32];
    const int m0 = blockIdx.y * 128, n0 = blockIdx.x * 128;
    const int t = threadIdx.x, lane = t & 63, w = t >> 6;
    const int wr = w >> 1, wc = w & 1;
    const int rl = lane & 15, g = lane >> 4;

    // staging geometry: each wave stages 32 rows (2 insts x 16 rows);
    // lane l sources row base+l/4, halves col (l&3)*8 (16B per lane, linear LDS dest)
    const int srow = w * 32 + (lane >> 2);
    const int scol = (lane & 3) * 8;
    int ar0 = m0 + srow;        ar0 = ar0 < Mm ? ar0 : Mm - 1;
    int ar1 = m0 + srow + 16;   ar1 = ar1 < Mm ? ar1 : Mm - 1;
    const half_t* ag0 = A + (size_t)ar0 * Kk + scol;
    const half_t* ag1 = A + (size_t)ar1 * Kk + scol;
    const half_t* bg0 = Bt + (size_t)(n0 + srow) * Kk + scol;
    const half_t* bg1 = Bt + (size_t)(n0 + srow + 16) * Kk + scol;
    half_t* asl0 = As + (w * 32) * 32;
    half_t* asl1 = As + (w * 32 + 16) * 32;
    half_t* bsl0 = Bs + (w * 32) * 32;
    half_t* bsl1 = Bs + (w * 32 + 16) * 32;

    f32x4 acc[4][4] = {};

    for (int k0 = 0; k0 < Kk; k0 += 32) {
        gload_lds16(ag0, asl0);
        gload_lds16(ag1, asl1);
        gload_lds16(bg0, bsl0);
        gload_lds16(bg1, bsl1);
        ag0 += 32; ag1 += 32; bg0 += 32; bg1 += 32;
        __syncthreads();

        half8 af[4], bf[4];
#pragma unroll
        for (int i = 0; i < 4; ++i)
            af[i] = *(const half8*)&As[(wr * 64 + i * 16 + rl) * 32 + g * 8];
#pragma unroll
        for (int j = 0; j < 4; ++j)
            bf[j] = *(const half8*)&Bs[(wc * 64 + j * 16 + rl) * 32 + g * 8];
#pragma unroll
        for (int i = 0; i < 4; ++i)
#pragma unroll
            for (int j = 0; j < 4; ++j)
                acc[i][j] = __builtin_amdgcn_mfma_f32_16x16x32_f16(af[i], bf[j], acc[i][j], 0, 0, 0);
        __syncthreads();
    }

#pragma unroll
    for (int i = 0; i < 4; ++i) {
        int rbase = m0 + wr * 64 + i * 16 + g * 4;
#pragma unroll
        for (int r = 0; r < 4; ++r) {
            int row = rbase + r;
            if (row >= Mm) continue;
            if (EPI == 4) {
#pragma unroll
                for (int j = 0; j < 4; j += 2) {
                    int ccbase = n0 + wc * 64 + j * 16;       // multiple of 32
                    int col = (ccbase >> 5) * 16 + rl;        // original a/g column
                    float a = acc[i][j][r];
                    float gv = acc[i][j + 1][r];
                    float sg = gv / (1.0f + expf(-gv));
                    Ch[(size_t)row * (Nn >> 1) + col] = (half_t)(a * sg);
                }
            } else {
#pragma unroll
                for (int j = 0; j < 4; ++j) {
                    int col = n0 + wc * 64 + j * 16 + rl;
                    float vvv = acc[i][j][r];
                    if (EPI == 0) {
                        Cf[(size_t)row * Nn + col] = vvv;
                    } else if (EPI == 1) {
                        if (col < 512) Cf[(size_t)row * 512 + col] = vvv;
                        else C2[(size_t)row * 128 + (col - 512)] = vvv + bias[col - 512];
                    } else if (EPI == 2) {
                        Cf[(size_t)row * Nn + col] += vvv;
                    }
                }
            }
        }
    }
}

// ---------------- rotary + l2norm -> fp16 (q-hat * 4) ----------------
// reads bq fp32 rows [(b*kN+n)*kH + h][64], writes Qh [b][h][576][64] fp16
__global__ void qrot_kernel(const float* __restrict__ q, half_t* __restrict__ Qh) {
    int row = blockIdx.x * 4 + (threadIdx.x >> 6);
    int lane = threadIdx.x & 63;
    int h = row % kH;
    int bn = row / kH;
    int b = bn / kN, n = bn % kN;
    float t = q[(size_t)row * kDH + lane];
    float partner = __shfl_xor(t, 1);
    if (lane < kROT) {
        float e = (float)(lane & ~1) / (float)kROT;
        float inv = powf(10000.0f, -e);
        float ang = (float)n * inv;
        float c = cosf(ang), s = sinf(ang);
        t = (lane & 1) ? fmaf(t, c, partner * s) : fmaf(t, c, -partner * s);
    }
    float ss = wave_sum(t * t);
    float sc = 4.0f / sqrtf(ss);
    Qh[(((size_t)b * kH + h) * kNKP + n) * kDH + lane] = (half_t)(t * sc);
}

// kv fp32 [(b,n)][128] -> Kh [b][576][64] fp16 (k-hat*4, zero pad), VTh [b][64][576] fp16
__global__ void krot_kernel(const float* __restrict__ kv, const float* __restrict__ nullkv,
                            half_t* __restrict__ Kh, half_t* __restrict__ VTh) {
    int row = blockIdx.x * 4 + (threadIdx.x >> 6);   // b*576 + jj
    int lane = threadIdx.x & 63;
    int b = row / kNKP, jj = row % kNKP;
    float tk = 0.f, tv = 0.f;
    if (jj == 0) {
        tk = nullkv[lane];
        tv = nullkv[64 + lane];
    } else if (jj < kNK) {
        size_t base = ((size_t)(b * kN + jj - 1)) * 128;
        tk = kv[base + lane];
        tv = kv[base + 64 + lane];
    }
    float partner = __shfl_xor(tk, 1);
    if (jj != 0 && jj < kNK && lane < kROT) {
        float e = (float)(lane & ~1) / (float)kROT;
        float inv = powf(10000.0f, -e);
        float ang = (float)(jj - 1) * inv;
        float c = cosf(ang), s = sinf(ang);
        tk = (lane & 1) ? fmaf(tk, c, partner * s) : fmaf(tk, c, -partner * s);
    }
    float ss = wave_sum(tk * tk);
    float sc = (jj < kNK) ? 4.0f / sqrtf(ss) : 0.f;
    Kh[(size_t)row * kDH + lane] = (half_t)(tk * sc);
    VTh[((size_t)b * kDH + lane) * kNKP + jj] = (half_t)tv;
}

// ---------------- relpos bias delta table: db[h][idx], idx = i-j+1 in [0,515] -------
__global__ void dbias_kernel(const float* __restrict__ emb, float* __restrict__ db) {
    int t = blockIdx.x * 256 + threadIdx.x;
    if (t >= kH * 516) return;
    int h = t / 516, idx = t % 516;
    int nn = idx - 1; if (nn < 0) nn = 0;
    int bucket;
    if (nn < 16) bucket = nn;
    else {
        float lf = logf((float)nn * (1.0f / 16.0f));
        int vl = 16 + (int)(lf / logf(8.0f) * 16.0f);
        bucket = vl < 31 ? vl : 31;
    }
    db[t] = emb[bucket * kH + h];
}

// ---------------- MFMA flash attention ----------------
// grid (qt=9, h=8, b=8), 256 threads = 4 waves, wave = 16 queries.
// Qh [b][h][576][64], Kh [b][576][64], VTh [b][64][576] all fp16 (q,k scaled by 4).
// o fp16 [(b*kN+n)][h*64+d]
__global__ __launch_bounds__(256)
void fattn_kernel(const half_t* __restrict__ Qh, const half_t* __restrict__ Kh,
                  const half_t* __restrict__ VTh, const float* __restrict__ dbias,
                  half_t* __restrict__ o) {
    const int qt = blockIdx.x, h = blockIdx.y, b = blockIdx.z;
    const int t = threadIdx.x, lane = t & 63, w = t >> 6;
    const int rl = lane & 15, g = lane >> 4;
    const int q0 = qt * 64, qw0 = q0 + w * 16;

    __shared__ half_t Ps[4][16][72];
    __shared__ float db[520];
    for (int i = t; i < 516; i += 256) db[i] = dbias[h * 516 + i];
    __syncthreads();

    // Q fragments (row = rl, k-offset = g*8), loop-invariant
    const half_t* qbase = Qh + (((size_t)b * kH + h) * kNKP + qw0 + rl) * kDH;
    half8 qa0 = *(const half8*)(qbase + g * 8);
    half8 qa1 = *(const half8*)(qbase + 32 + g * 8);

    float m[4] = {-1e30f, -1e30f, -1e30f, -1e30f};
    float l[4] = {0.f, 0.f, 0.f, 0.f};
    f32x4 Oa[4] = {};

    const int wktiles = min((qw0 + 16) / 64 + 1, kNKP / 64);

    for (int kt = 0; kt < wktiles; ++kt) {
        const int jt = kt * 64;
        // QK^T: 4 frags of 16 keys
        f32x4 sc[4];
#pragma unroll
        for (int f = 0; f < 4; ++f) {
            const half_t* kp = Kh + ((size_t)b * kNKP + jt + f * 16 + rl) * kDH + g * 8;
            half8 kb0 = *(const half8*)kp;
            half8 kb1 = *(const half8*)(kp + 32);
            f32x4 a = {};
            a = __builtin_amdgcn_mfma_f32_16x16x32_f16(qa0, kb0, a, 0, 0, 0);
            a = __builtin_amdgcn_mfma_f32_16x16x32_f16(qa1, kb1, a, 0, 0, 0);
            sc[f] = a;
        }
        // bias + causal mask + tile row-max
        float tm[4] = {-1e30f, -1e30f, -1e30f, -1e30f};
#pragma unroll
        for (int f = 0; f < 4; ++f) {
            int jb = jt + f * 16 + rl;
#pragma unroll
            for (int r = 0; r < 4; ++r) {
                int qq = qw0 + 4 * g + r;
                int idx = qq - jb + 1;
                int ic = idx < 0 ? 0 : (idx > 515 ? 515 : idx);
                float s = sc[f][r] + db[ic];
                s = (idx < 0) ? -1e30f : s;
                sc[f][r] = s;
                tm[r] = fmaxf(tm[r], s);
            }
        }
#pragma unroll
        for (int off = 1; off < 16; off <<= 1)
#pragma unroll
            for (int r = 0; r < 4; ++r) tm[r] = fmaxf(tm[r], __shfl_xor(tm[r], off));
        // online softmax update
        float scal[4], tsum[4];
#pragma unroll
        for (int r = 0; r < 4; ++r) {
            float nm = fmaxf(m[r], tm[r]);
            scal[r] = __expf(m[r] - nm);
            m[r] = nm;
            tsum[r] = 0.f;
        }
#pragma unroll
        for (int f = 0; f < 4; ++f)
#pragma unroll
            for (int r = 0; r < 4; ++r) {
                float p = __expf(sc[f][r] - m[r]);
                tsum[r] += p;
                Ps[w][4 * g + r][f * 16 + rl] = (half_t)p;
            }
#pragma unroll
        for (int r = 0; r < 4; ++r) l[r] = l[r] * scal[r] + tsum[r];
#pragma unroll
        for (int fd = 0; fd < 4; ++fd)
#pragma unroll
            for (int r = 0; r < 4; ++r) Oa[fd][r] *= scal[r];
        // P A-frags from wave-private LDS
        half8 pa0 = *(const half8*)&Ps[w][rl][g * 8];
        half8 pa1 = *(const half8*)&Ps[w][rl][32 + g * 8];
        // PV: O += P @ V  (B-frag rows = d from VTh)
#pragma unroll
        for (int fd = 0; fd < 4; ++fd) {
            const half_t* vp = VTh + ((size_t)b * kDH + fd * 16 + rl) * kNKP + jt + g * 8;
            half8 vb0 = *(const half8*)vp;
            half8 vb1 = *(const half8*)(vp + 32);
            Oa[fd] = __builtin_amdgcn_mfma_f32_16x16x32_f16(pa0, vb0, Oa[fd], 0, 0, 0);
            Oa[fd] = __builtin_amdgcn_mfma_f32_16x16x32_f16(pa1, vb1, Oa[fd], 0, 0, 0);
        }
    }

    // final: reduce l across the 16-lane col group, store O / l
    float inv[4];
#pragma unroll
    for (int r = 0; r < 4; ++r) {
        float L = l[r];
#pragma unroll
        for (int off = 1; off < 16; off <<= 1) L += __shfl_xor(L, off);
        inv[r] = 1.0f / L;
    }
#pragma unroll
    for (int fd = 0; fd < 4; ++fd)
#pragma unroll
        for (int r = 0; r < 4; ++r) {
            int qq = qw0 + 4 * g + r;
            if (qq < kN)
                o[((size_t)(b * kN + qq) * kH + h) * kDH + fd * 16 + rl] =
                    (half_t)(Oa[fd][r] * inv[r]);
        }
}

}  // namespace

extern "C" void kernel_launch(void* const* d_in, const int* in_sizes, int n_in,
                              void* d_out, int out_size, void* d_ws, size_t ws_size,
                              hipStream_t stream) {
    const float* x_in   = (const float*)d_in[0];
    const float* attn_g = (const float*)d_in[1];
    const float* Wq     = (const float*)d_in[2];
    const float* Wkv    = (const float*)d_in[3];
    const float* bkv    = (const float*)d_in[4];
    const float* nullkv = (const float*)d_in[5];
    const float* Wo     = (const float*)d_in[6];
    const float* out_g  = (const float*)d_in[7];
    const float* ff_g   = (const float*)d_in[8];
    const float* Wff1   = (const float*)d_in[9];
    const float* Wff2   = (const float*)d_in[10];
    const float* emb    = (const float*)d_in[11];
    const float* fin_g  = (const float*)d_in[12];
    const float* Wproj  = (const float*)d_in[13];
    float* out = (float*)d_out;

    char* wsb = (char*)d_ws;
    size_t off = 0;
    auto alloc = [&](size_t bytes) -> void* {
        void* p = wsb + off;
        off += (bytes + 255) & ~(size_t)255;
        return p;
    };
    float*  bx    = (float*)alloc((size_t)kM * kD * 4);
    float*  bt    = (float*)alloc((size_t)kM * kD * 4);
    half_t* bxn   = (half_t*)alloc((size_t)kM * kD * 2);       // LN out, fp16
    float*  bq    = (float*)alloc((size_t)kM * 512 * 4);
    half_t* bo    = (half_t*)alloc((size_t)kM * 512 * 2);      // attn out, fp16
    float*  bkvb  = (float*)alloc((size_t)kM * 128 * 4);
    half_t* Qh    = (half_t*)alloc((size_t)kB * kH * kNKP * kDH * 2);
    half_t* Kh    = (half_t*)alloc((size_t)kB * kNKP * kDH * 2);
    half_t* VTh   = (half_t*)alloc((size_t)kB * kDH * kNKP * 2);
    float*  dbias = (float*)alloc((size_t)kH * 516 * 4);
    half_t* bg    = (half_t*)alloc((size_t)kM * kFF * 2);      // a*silu(g), fp16
    half_t* WqkvT = (half_t*)alloc((size_t)640 * kD * 2);      // per-layer
    half_t* WoT   = (half_t*)alloc((size_t)kD * 512 * 2);
    half_t* Wff1T = (half_t*)alloc((size_t)2 * kFF * kD * 2);  // interleaved a/g
    half_t* Wff2T = (half_t*)alloc((size_t)kD * kFF * 2);

    hipMemcpyAsync(bx, x_in, (size_t)kM * kD * 4, hipMemcpyDeviceToDevice, stream);
    dbias_kernel<<<(kH * 516 + 255) / 256, 256, 0, stream>>>(emb, dbias);

    const int mt = (kM + 127) / 128;  // 33 row tiles

    for (int l = 0; l < kL; ++l) {
        // convert this layer's weights (fp32 [K][N] -> fp16 B^T [N][K])
        tcvt_kernel<0><<<dim3(512 / 32, kD / 32), 256, 0, stream>>>(
            Wq + (size_t)l * kD * 512, WqkvT, kD, 512, kD, 0);
        tcvt_kernel<0><<<dim3(128 / 32, kD / 32), 256, 0, stream>>>(
            Wkv + (size_t)l * kD * 128, WqkvT, kD, 128, kD, 512);
        tcvt_kernel<0><<<dim3(kD / 32, 512 / 32), 256, 0, stream>>>(
            Wo + (size_t)l * 512 * kD, WoT, 512, kD, 512, 0);
        tcvt_kernel<1><<<dim3(2 * kFF / 32, kD / 32), 256, 0, stream>>>(
            Wff1 + (size_t)l * kD * 2 * kFF, Wff1T, kD, 2 * kFF, kD, 0);
        tcvt_kernel<0><<<dim3(kD / 32, kFF / 32), 256, 0, stream>>>(
            Wff2 + (size_t)l * kFF * kD, Wff2T, kFF, kD, kFF, 0);

        ln_kernel<0><<<kM, 256, 0, stream>>>(bx, attn_g + (size_t)l * kD, bxn);
        mm_kernel<1><<<dim3(640 / 128, mt), 256, 0, stream>>>(
            bxn, WqkvT, bq, nullptr, bkvb, bkv + (size_t)l * 128, kM, 640, kD);
        qrot_kernel<<<kM * kH / 4, 256, 0, stream>>>(bq, Qh);
        krot_kernel<<<kB * kNKP / 4, 256, 0, stream>>>(bkvb, nullkv + (size_t)l * 128, Kh, VTh);
        fattn_kernel<<<dim3(kNKP / 64, kH, kB), 256, 0, stream>>>(Qh, Kh, VTh, dbias, bo);
        mm_kernel<0><<<dim3(kD / 128, mt), 256, 0, stream>>>(
            bo, WoT, bt, nullptr, nullptr, nullptr, kM, kD, 512);
        ln_add_ln_kernel<<<kM, 256, 0, stream>>>(
            bt, out_g + (size_t)l * kD, bx, ff_g + (size_t)l * kD, bxn);
        mm_kernel<4><<<dim3(2 * kFF / 128, mt), 256, 0, stream>>>(
            bxn, Wff1T, nullptr, bg, nullptr, nullptr, kM, 2 * kFF, kD);
        mm_kernel<2><<<dim3(kD / 128, mt), 256, 0, stream>>>(
            bg, Wff2T, bx, nullptr, nullptr, nullptr, kM, kD, kFF);
    }

    ln_kernel<2><<<kM, 256, 0, stream>>>(bx, fin_g, bxn);
    // reuse Wff1T region for Wproj^T (last FF1 GEMM already consumed it)
    tcvt_kernel<0><<<dim3(kD / 32, kD / 32), 256, 0, stream>>>(Wproj, (half_t*)Wff1T, kD, kD, kD, 0);
    mm_kernel<0><<<dim3(kD / 128, mt), 256, 0, stream>>>(
        bxn, (half_t*)Wff1T, out, nullptr, nullptr, nullptr, kM, kD, kD);
}